// Round 1
// baseline (465.403 us; speedup 1.0000x reference)
//
#include <hip/hip_runtime.h>
#include <hip/hip_bf16.h>

// RNN-T joint network. B=4 T=256 U=64 D=512 J=512 V=1024.
//   Pe = enc @ W_enc^T + b_enc   (1024 x 512)  fp32 in ws
//   Pd = dec @ W_dec^T           (256  x 512)  fp32 in ws
//   out[m,:] = tanh(Pe[m>>6] + Pd[(m>>14)*64 + (m&63)]) @ W_out^T + b_out
//              (65536 x 1024) fp32, tanh FUSED into main-GEMM A-staging
//              (H is never materialized: Pe/Pd are L2-resident, recompute
//               of tanh per n-tile is ~14 us of v_exp_f32 overlapped w/ MFMA)
//
// Inputs may be fp32 or bf16 (detected at runtime per tensor); normalized to
// bf16 copies in ws for the MFMA pipeline. Output written as fp32.

typedef __attribute__((ext_vector_type(8))) short short8;     // 8 bf16
typedef __attribute__((ext_vector_type(4))) float f32x4;

#define SZ0 524288
#define SZ1 131072
#define SZ2 262144
#define SZ3 512
#define SZ4 262144
#define SZ5 524288
#define SZ6 1024
#define CU0 0
#define CU1 524288
#define CU2 655360
#define CU3 917504
#define CU4 918016
#define CU5 1180160
#define CU6 1704448
#define CTOT 1705472

// ---------------------------------------------------------------------------
// Runtime dtype detection: scan each tensor's first <=1024 ushorts as bf16.
// fp32 buffers expose random mantissa bytes as bf16 exponents >= 0x8E w.h.p.;
// genuine bf16 N(0,1)/uniform data never exceeds |v|~6. flags[t]=1 -> fp32.
// ---------------------------------------------------------------------------
__global__ void detect_kernel(const void* p0, const void* p1, const void* p2,
                              const void* p3, const void* p4, const void* p5,
                              const void* p6, int* flags) {
  const void* ps[7] = {p0, p1, p2, p3, p4, p5, p6};
  const int sz[7] = {SZ0, SZ1, SZ2, SZ3, SZ4, SZ5, SZ6};
  const int w = threadIdx.x >> 6;
  const int l = threadIdx.x & 63;
  if (w >= 7) return;
  const unsigned short* u = (const unsigned short*)ps[w];
  const int lim = sz[w] < 1024 ? sz[w] : 1024;
  int bad = 0;
  for (int j = l; j < lim; j += 64) {
    const unsigned e = (u[j] >> 7) & 0xFFu;
    if (e >= 0x8Eu) bad = 1;
  }
  const unsigned long long b = __ballot(bad);
  if (l == 0) flags[w] = (b != 0ULL) ? 1 : 0;
}

// Normalize all 7 inputs into one contiguous bf16 blob.
__global__ __launch_bounds__(256) void convert_kernel(
    const void* p0, const void* p1, const void* p2, const void* p3,
    const void* p4, const void* p5, const void* p6,
    const int* __restrict__ flags, __hip_bfloat16* __restrict__ dst) {
  const int gid = blockIdx.x * 256 + threadIdx.x;
  if (gid >= CTOT) return;
  int t, local;
  const void* p;
  if (gid < CU1)      { t = 0; local = gid - CU0; p = p0; }
  else if (gid < CU2) { t = 1; local = gid - CU1; p = p1; }
  else if (gid < CU3) { t = 2; local = gid - CU2; p = p2; }
  else if (gid < CU4) { t = 3; local = gid - CU3; p = p3; }
  else if (gid < CU5) { t = 4; local = gid - CU4; p = p4; }
  else if (gid < CU6) { t = 5; local = gid - CU5; p = p5; }
  else                { t = 6; local = gid - CU6; p = p6; }
  __hip_bfloat16 v;
  if (flags[t])
    v = __float2bfloat16(((const float*)p)[local]);
  else
    v = ((const __hip_bfloat16*)p)[local];
  dst[gid] = v;
}

// ---------------------------------------------------------------------------
// m97-structure GEMM body: C[M,N] = A[M,K] * B[N,K]^T (+bias), fp32 out.
// 128x128 tile, BK=64, 4 waves 2x2, each wave 4x4 of 16x16x32 MFMA.
// Shared by the two small projection GEMMs (one combined launch).
// ---------------------------------------------------------------------------
__device__ __forceinline__ void gemm_bt_body(
    const __hip_bfloat16* __restrict__ A, const __hip_bfloat16* __restrict__ Bw,
    const __hip_bfloat16* __restrict__ bias, float* __restrict__ C,
    int M, int N, int K, int bid,
    __hip_bfloat16* sA, __hip_bfloat16* sB) {
  const int tid = threadIdx.x;
  const int w = tid >> 6;
  const int l = tid & 63;
  const int ntiles = N >> 7;
  const int mt = bid / ntiles;
  const int nt = bid % ntiles;
  const int m0 = mt << 7;
  const int n0 = nt << 7;
  const int wm = (w >> 1) << 6;
  const int wn = (w & 1) << 6;
  const int r16 = l & 15;
  const int q = l >> 4;

  f32x4 acc[4][4] = {};

  const int srow_in = l >> 3;
  const int scol = (l & 7) << 3;

  for (int k0 = 0; k0 < K; k0 += 64) {
#pragma unroll
    for (int i = 0; i < 4; ++i) {
      const int c = (w << 2) + i;
      const int row = (c << 3) + srow_in;
      const __hip_bfloat16* gA = A + (size_t)(m0 + row) * K + k0 + scol;
      const __hip_bfloat16* gB = Bw + (size_t)(n0 + row) * K + k0 + scol;
      __builtin_amdgcn_global_load_lds(
          (const __attribute__((address_space(1))) void*)gA,
          (__attribute__((address_space(3))) void*)(sA + (c << 9) + (l << 3)),
          16, 0, 0);
      __builtin_amdgcn_global_load_lds(
          (const __attribute__((address_space(1))) void*)gB,
          (__attribute__((address_space(3))) void*)(sB + (c << 9) + (l << 3)),
          16, 0, 0);
    }
    __syncthreads();

#pragma unroll
    for (int kk = 0; kk < 2; ++kk) {
      const int kc = (kk << 5) + (q << 3);
      short8 af[4], bf[4];
#pragma unroll
      for (int mi = 0; mi < 4; ++mi)
        af[mi] = *(const short8*)(sA + (wm + (mi << 4) + r16) * 64 + kc);
#pragma unroll
      for (int ni = 0; ni < 4; ++ni)
        bf[ni] = *(const short8*)(sB + (wn + (ni << 4) + r16) * 64 + kc);
#pragma unroll
      for (int mi = 0; mi < 4; ++mi)
#pragma unroll
        for (int ni = 0; ni < 4; ++ni)
          acc[mi][ni] = __builtin_amdgcn_mfma_f32_16x16x32_bf16(
              af[mi], bf[ni], acc[mi][ni], 0, 0, 0);
    }
    __syncthreads();
  }

  // C/D layout: col = lane&15, row = quad*4 + reg.
#pragma unroll
  for (int ni = 0; ni < 4; ++ni) {
    const int col = n0 + wn + (ni << 4) + r16;
    const float bc = bias ? __bfloat162float(bias[col]) : 0.0f;
#pragma unroll
    for (int mi = 0; mi < 4; ++mi) {
      const int rowb = m0 + wm + (mi << 4) + (q << 2);
#pragma unroll
      for (int i = 0; i < 4; ++i)
        C[(size_t)(rowb + i) * N + col] = acc[mi][ni][i] + bc;
    }
  }
}

// Pe (32 blocks) and Pd (8 blocks) in one 40-block launch.
__global__ __launch_bounds__(256) void proj_kernel(
    const __hip_bfloat16* __restrict__ enc, const __hip_bfloat16* __restrict__ Wenc,
    const __hip_bfloat16* __restrict__ benc,
    const __hip_bfloat16* __restrict__ dec, const __hip_bfloat16* __restrict__ Wdec,
    float* __restrict__ Pe, float* __restrict__ Pd) {
  __shared__ __align__(16) __hip_bfloat16 sA[128 * 64];
  __shared__ __align__(16) __hip_bfloat16 sB[128 * 64];
  if (blockIdx.x < 32)
    gemm_bt_body(enc, Wenc, benc, Pe, 1024, 512, 512, blockIdx.x, sA, sB);
  else
    gemm_bt_body(dec, Wdec, nullptr, Pd, 256, 512, 512, blockIdx.x - 32, sA, sB);
}

// ---------------------------------------------------------------------------
// Main GEMM, tanh fused into A-tile staging (H never hits memory).
// M=65536, N=1024, K=512 fixed. fp32 out.
// Order per K-step: issue B global_load_lds first (16B async DMA), then the
// A-tile tanh VALU work overlaps the loads in flight, then one barrier.
// ---------------------------------------------------------------------------
__global__ __launch_bounds__(256) void gemm_fused(
    const float* __restrict__ Pe, const float* __restrict__ Pd,
    const __hip_bfloat16* __restrict__ Bw,
    const __hip_bfloat16* __restrict__ bias, float* __restrict__ out) {
  __shared__ __align__(16) __hip_bfloat16 sA[128 * 64];
  __shared__ __align__(16) __hip_bfloat16 sB[128 * 64];
  const int tid = threadIdx.x;
  const int w = tid >> 6;
  const int l = tid & 63;
  const int mt = blockIdx.x >> 3;
  const int nt = blockIdx.x & 7;
  const int m0 = mt << 7;
  const int n0 = nt << 7;
  const int wm = (w >> 1) << 6;
  const int wn = (w & 1) << 6;
  const int r16 = l & 15;
  const int q = l >> 4;
  f32x4 acc[4][4] = {};
  const int arow = tid >> 3;
  const int acol = (tid & 7) << 3;

  for (int k0 = 0; k0 < 512; k0 += 64) {
#pragma unroll
    for (int i = 0; i < 4; ++i) {
      const int c = (w << 2) + i;
      const int row = (c << 3) + (l >> 3);
      const int col = (l & 7) << 3;
      __builtin_amdgcn_global_load_lds(
          (const __attribute__((address_space(1))) void*)(
              Bw + (size_t)(n0 + row) * 512 + k0 + col),
          (__attribute__((address_space(3))) void*)(sB + (c << 9) + (l << 3)),
          16, 0, 0);
    }
#pragma unroll
    for (int c2 = 0; c2 < 4; ++c2) {
      const int row = arow + (c2 << 5);
      const int m = m0 + row;
      const int e = m >> 6;
      const int dd = ((m >> 14) << 6) | (m & 63);
      const float* pe = Pe + (size_t)e * 512 + k0 + acol;
      const float* pd = Pd + (size_t)dd * 512 + k0 + acol;
      const f32x4 e0 = *(const f32x4*)pe, e1 = *(const f32x4*)(pe + 4);
      const f32x4 g0 = *(const f32x4*)pd, g1 = *(const f32x4*)(pd + 4);
      short8 hv;
#pragma unroll
      for (int j = 0; j < 4; ++j) {
        float s = e0[j] + g0[j];
        float t = 1.0f - 2.0f / (__expf(2.0f * s) + 1.0f);
        __hip_bfloat16 hb = __float2bfloat16(t);
        hv[j] = *(const short*)&hb;
        s = e1[j] + g1[j];
        t = 1.0f - 2.0f / (__expf(2.0f * s) + 1.0f);
        hb = __float2bfloat16(t);
        hv[4 + j] = *(const short*)&hb;
      }
      *(short8*)(sA + row * 64 + acol) = hv;
    }
    __syncthreads();
#pragma unroll
    for (int kk = 0; kk < 2; ++kk) {
      const int kc = (kk << 5) + (q << 3);
      short8 af[4], bf[4];
#pragma unroll
      for (int mi = 0; mi < 4; ++mi)
        af[mi] = *(const short8*)(sA + (wm + (mi << 4) + r16) * 64 + kc);
#pragma unroll
      for (int ni = 0; ni < 4; ++ni)
        bf[ni] = *(const short8*)(sB + (wn + (ni << 4) + r16) * 64 + kc);
#pragma unroll
      for (int mi = 0; mi < 4; ++mi)
#pragma unroll
        for (int ni = 0; ni < 4; ++ni)
          acc[mi][ni] = __builtin_amdgcn_mfma_f32_16x16x32_bf16(
              af[mi], bf[ni], acc[mi][ni], 0, 0, 0);
    }
    __syncthreads();
  }

#pragma unroll
  for (int ni = 0; ni < 4; ++ni) {
    const int col = n0 + wn + (ni << 4) + r16;
    const float bc = __bfloat162float(bias[col]);
#pragma unroll
    for (int mi = 0; mi < 4; ++mi) {
      const int rowb = m0 + wm + (mi << 4) + (q << 2);
#pragma unroll
      for (int i = 0; i < 4; ++i)
        out[(size_t)(rowb + i) * 1024 + col] = acc[mi][ni][i] + bc;
    }
  }
}

// ---------------------------------------------------------------------------
extern "C" void kernel_launch(void* const* d_in, const int* in_sizes, int n_in,
                              void* d_out, int out_size, void* d_ws,
                              size_t ws_size, hipStream_t stream) {
  // ws layout (bytes):
  //   0      : flags (7 ints)
  //   256    : bf16 input copies (CTOT*2 = 3.26 MB)
  //   4 MB   : Pe fp32 (2 MB)
  //   6 MB   : Pd fp32 (0.5 MB)
  char* ws = (char*)d_ws;
  int* flags = (int*)ws;
  __hip_bfloat16* cp = (__hip_bfloat16*)(ws + 256);
  float* Pe = (float*)(ws + (4ull << 20));
  float* Pd = (float*)(ws + (6ull << 20));

  detect_kernel<<<dim3(1), dim3(512), 0, stream>>>(
      d_in[0], d_in[1], d_in[2], d_in[3], d_in[4], d_in[5], d_in[6], flags);
  convert_kernel<<<dim3((CTOT + 255) / 256), dim3(256), 0, stream>>>(
      d_in[0], d_in[1], d_in[2], d_in[3], d_in[4], d_in[5], d_in[6], flags, cp);

  const __hip_bfloat16* enc_c = cp + CU0;
  const __hip_bfloat16* dec_c = cp + CU1;
  const __hip_bfloat16* Wenc_c = cp + CU2;
  const __hip_bfloat16* benc_c = cp + CU3;
  const __hip_bfloat16* Wdec_c = cp + CU4;
  const __hip_bfloat16* Wout_c = cp + CU5;
  const __hip_bfloat16* bout_c = cp + CU6;

  proj_kernel<<<dim3(40), dim3(256), 0, stream>>>(enc_c, Wenc_c, benc_c,
                                                  dec_c, Wdec_c, Pe, Pd);
  gemm_fused<<<dim3(4096), dim3(256), 0, stream>>>(
      Pe, Pd, Wout_c, bout_c, (float*)d_out);
}

// Round 2
// 410.214 us; speedup vs baseline: 1.1345x; 1.1345x over previous
//
#include <hip/hip_runtime.h>
#include <hip/hip_bf16.h>

// RNN-T joint network. B=4 T=256 U=64 D=512 J=512 V=1024.
//   Pe = enc @ W_enc^T + b_enc   (1024 x 512)  fp32 in ws
//   Pd = dec @ W_dec^T           (256  x 512)  fp32 in ws
//   out[m,:] = tanh(Pe[m>>6] + Pd[(m>>14)*64 + (m&63)]) @ W_out^T + b_out
//
// Main kernel (gemm_joint): one block = 128 H-rows, FULL K resident in LDS.
//   Phase 1: tanh(Pe+Pd) -> sH[128][512] bf16, computed ONCE per row
//            (round-1 lesson: per-nt recompute was 8x redundant VALU, 68% VALUBusy).
//   Phase 2: nt-loop x4 over W_out (L2-resident, 1MB), BK=32 double-buffered
//            sB via global_load_lds, 2-phase pipeline (stage-next / compute /
//            vmcnt0+barrier). H never touches global memory.
// LDS: sH 128KB + sB 2x16KB = 160KB (full CU LDS; AITER fmha precedent).
// Swizzles (rule #21, both-sides involutions):
//   sH: chunk16 index c stored at c ^ (row&7)   (ds_write side = read side)
//   sB: linear gload_lds dest; SOURCE col pre-swizzled by ^ (row&3); read ^.

typedef __attribute__((ext_vector_type(8))) short short8;     // 8 bf16
typedef __attribute__((ext_vector_type(4))) float f32x4;

#define SZ0 524288
#define SZ1 131072
#define SZ2 262144
#define SZ3 512
#define SZ4 262144
#define SZ5 524288
#define SZ6 1024
#define CU0 0
#define CU1 524288
#define CU2 655360
#define CU3 917504
#define CU4 918016
#define CU5 1180160
#define CU6 1704448
#define CTOT 1705472

// ---------------------------------------------------------------------------
// Runtime dtype detection (unchanged).
// ---------------------------------------------------------------------------
__global__ void detect_kernel(const void* p0, const void* p1, const void* p2,
                              const void* p3, const void* p4, const void* p5,
                              const void* p6, int* flags) {
  const void* ps[7] = {p0, p1, p2, p3, p4, p5, p6};
  const int sz[7] = {SZ0, SZ1, SZ2, SZ3, SZ4, SZ5, SZ6};
  const int w = threadIdx.x >> 6;
  const int l = threadIdx.x & 63;
  if (w >= 7) return;
  const unsigned short* u = (const unsigned short*)ps[w];
  const int lim = sz[w] < 1024 ? sz[w] : 1024;
  int bad = 0;
  for (int j = l; j < lim; j += 64) {
    const unsigned e = (u[j] >> 7) & 0xFFu;
    if (e >= 0x8Eu) bad = 1;
  }
  const unsigned long long b = __ballot(bad);
  if (l == 0) flags[w] = (b != 0ULL) ? 1 : 0;
}

__global__ __launch_bounds__(256) void convert_kernel(
    const void* p0, const void* p1, const void* p2, const void* p3,
    const void* p4, const void* p5, const void* p6,
    const int* __restrict__ flags, __hip_bfloat16* __restrict__ dst) {
  const int gid = blockIdx.x * 256 + threadIdx.x;
  if (gid >= CTOT) return;
  int t, local;
  const void* p;
  if (gid < CU1)      { t = 0; local = gid - CU0; p = p0; }
  else if (gid < CU2) { t = 1; local = gid - CU1; p = p1; }
  else if (gid < CU3) { t = 2; local = gid - CU2; p = p2; }
  else if (gid < CU4) { t = 3; local = gid - CU3; p = p3; }
  else if (gid < CU5) { t = 4; local = gid - CU4; p = p4; }
  else if (gid < CU6) { t = 5; local = gid - CU5; p = p5; }
  else                { t = 6; local = gid - CU6; p = p6; }
  __hip_bfloat16 v;
  if (flags[t])
    v = __float2bfloat16(((const float*)p)[local]);
  else
    v = ((const __hip_bfloat16*)p)[local];
  dst[gid] = v;
}

// ---------------------------------------------------------------------------
// m97-structure GEMM body for the two small projections (unchanged).
// ---------------------------------------------------------------------------
__device__ __forceinline__ void gemm_bt_body(
    const __hip_bfloat16* __restrict__ A, const __hip_bfloat16* __restrict__ Bw,
    const __hip_bfloat16* __restrict__ bias, float* __restrict__ C,
    int M, int N, int K, int bid,
    __hip_bfloat16* sA, __hip_bfloat16* sB) {
  const int tid = threadIdx.x;
  const int w = tid >> 6;
  const int l = tid & 63;
  const int ntiles = N >> 7;
  const int mt = bid / ntiles;
  const int nt = bid % ntiles;
  const int m0 = mt << 7;
  const int n0 = nt << 7;
  const int wm = (w >> 1) << 6;
  const int wn = (w & 1) << 6;
  const int r16 = l & 15;
  const int q = l >> 4;

  f32x4 acc[4][4] = {};

  const int srow_in = l >> 3;
  const int scol = (l & 7) << 3;

  for (int k0 = 0; k0 < K; k0 += 64) {
#pragma unroll
    for (int i = 0; i < 4; ++i) {
      const int c = (w << 2) + i;
      const int row = (c << 3) + srow_in;
      const __hip_bfloat16* gA = A + (size_t)(m0 + row) * K + k0 + scol;
      const __hip_bfloat16* gB = Bw + (size_t)(n0 + row) * K + k0 + scol;
      __builtin_amdgcn_global_load_lds(
          (const __attribute__((address_space(1))) void*)gA,
          (__attribute__((address_space(3))) void*)(sA + (c << 9) + (l << 3)),
          16, 0, 0);
      __builtin_amdgcn_global_load_lds(
          (const __attribute__((address_space(1))) void*)gB,
          (__attribute__((address_space(3))) void*)(sB + (c << 9) + (l << 3)),
          16, 0, 0);
    }
    __syncthreads();

#pragma unroll
    for (int kk = 0; kk < 2; ++kk) {
      const int kc = (kk << 5) + (q << 3);
      short8 af[4], bf[4];
#pragma unroll
      for (int mi = 0; mi < 4; ++mi)
        af[mi] = *(const short8*)(sA + (wm + (mi << 4) + r16) * 64 + kc);
#pragma unroll
      for (int ni = 0; ni < 4; ++ni)
        bf[ni] = *(const short8*)(sB + (wn + (ni << 4) + r16) * 64 + kc);
#pragma unroll
      for (int mi = 0; mi < 4; ++mi)
#pragma unroll
        for (int ni = 0; ni < 4; ++ni)
          acc[mi][ni] = __builtin_amdgcn_mfma_f32_16x16x32_bf16(
              af[mi], bf[ni], acc[mi][ni], 0, 0, 0);
    }
    __syncthreads();
  }

#pragma unroll
  for (int ni = 0; ni < 4; ++ni) {
    const int col = n0 + wn + (ni << 4) + r16;
    const float bc = bias ? __bfloat162float(bias[col]) : 0.0f;
#pragma unroll
    for (int mi = 0; mi < 4; ++mi) {
      const int rowb = m0 + wm + (mi << 4) + (q << 2);
#pragma unroll
      for (int i = 0; i < 4; ++i)
        C[(size_t)(rowb + i) * N + col] = acc[mi][ni][i] + bc;
    }
  }
}

__global__ __launch_bounds__(256) void proj_kernel(
    const __hip_bfloat16* __restrict__ enc, const __hip_bfloat16* __restrict__ Wenc,
    const __hip_bfloat16* __restrict__ benc,
    const __hip_bfloat16* __restrict__ dec, const __hip_bfloat16* __restrict__ Wdec,
    float* __restrict__ Pe, float* __restrict__ Pd) {
  __shared__ __align__(16) __hip_bfloat16 sA[128 * 64];
  __shared__ __align__(16) __hip_bfloat16 sB[128 * 64];
  if (blockIdx.x < 32)
    gemm_bt_body(enc, Wenc, benc, Pe, 1024, 512, 512, blockIdx.x, sA, sB);
  else
    gemm_bt_body(dec, Wdec, nullptr, Pd, 256, 512, 512, blockIdx.x - 32, sA, sB);
}

// ---------------------------------------------------------------------------
// Main fused GEMM: full-K H in LDS, tanh once, nt-loop over W_out.
// grid = 512 blocks (1/CU, 2 passes), 512 threads (8 waves).
// Wave tile 64x64: waves (w>>2) in M (0/64), (w&3) in N (0/64/128/192).
// Per iter (nt,k0): stage next sB (2 gload_lds/thread), 8 ds_read_b128,
// 16 MFMA, then vmcnt0+barrier. 64 iters total (4 nt x 16 k0, BK=32).
// ---------------------------------------------------------------------------
__global__ __launch_bounds__(512, 2) void gemm_joint(
    const float* __restrict__ Pe, const float* __restrict__ Pd,
    const __hip_bfloat16* __restrict__ Bw,
    const __hip_bfloat16* __restrict__ bias, float* __restrict__ out) {
  __shared__ __align__(16) __hip_bfloat16 sH[128 * 512];   // 128 KB
  __shared__ __align__(16) __hip_bfloat16 sB[2][256 * 32]; // 2 x 16 KB

  const int t = threadIdx.x;
  const int w = t >> 6;
  const int l = t & 63;
  const int r16 = l & 15;
  const int q = l >> 4;
  const int m0 = blockIdx.x << 7;

  // STAGE: fill sB[buf] with W_out tile (nt, k0), source col pre-swizzled so
  // a swizzled READ of the linear gload_lds dest recovers the true layout.
  auto stage = [&](int iter, int buf) {
    const int n0 = (iter >> 4) << 8;
    const int k0 = (iter & 15) << 5;
#pragma unroll
    for (int j = 0; j < 2; ++j) {
      const int chunk = (w << 7) + (j << 6) + l;   // 0..1023 (row*4 + cc)
      const int row = chunk >> 2;
      const int cc = chunk & 3;
      const __hip_bfloat16* src =
          Bw + (size_t)(n0 + row) * 512 + k0 + ((cc ^ (row & 3)) << 3);
      __builtin_amdgcn_global_load_lds(
          (const __attribute__((address_space(1))) void*)src,
          (__attribute__((address_space(3))) void*)(&sB[buf][0] + (chunk << 3)),
          16, 0, 0);
    }
  };

  // Prologue: issue first B-tile, then tanh phase hides its latency.
  stage(0, 0);

  // Phase 1: H = tanh(Pe[e] + Pd[d]) -> sH, each (row, chunk16) exactly once.
  {
    const int r = t & 127;          // H row
    const int seg = t >> 7;         // 0..3, k-segment of 128
    const int m = m0 + r;
    const int e = m >> 6;
    const int d = ((m >> 14) << 6) | (r & 63);
    const float* pe = Pe + (size_t)e * 512 + (seg << 7);
    const float* pd = Pd + (size_t)d * 512 + (seg << 7);
#pragma unroll
    for (int i = 0; i < 16; ++i) {
      const int cc = (seg << 4) + i;            // chunk16 index 0..63
      const f32x4 a0 = *(const f32x4*)(pe + (i << 3));
      const f32x4 a1 = *(const f32x4*)(pe + (i << 3) + 4);
      const f32x4 b0 = *(const f32x4*)(pd + (i << 3));
      const f32x4 b1 = *(const f32x4*)(pd + (i << 3) + 4);
      short8 hv;
#pragma unroll
      for (int jj = 0; jj < 4; ++jj) {
        float s = a0[jj] + b0[jj];
        float tv = 1.0f - 2.0f / (__expf(2.0f * s) + 1.0f);
        __hip_bfloat16 hb = __float2bfloat16(tv);
        hv[jj] = *(const short*)&hb;
        s = a1[jj] + b1[jj];
        tv = 1.0f - 2.0f / (__expf(2.0f * s) + 1.0f);
        hb = __float2bfloat16(tv);
        hv[4 + jj] = *(const short*)&hb;
      }
      *(short8*)(sH + (r << 9) + ((cc ^ (r & 7)) << 3)) = hv;
    }
  }
  __syncthreads();  // drains vmcnt (stage 0) + lgkmcnt (sH writes)

  const int wm = (w >> 2) << 6;   // 0 or 64
  const int wn = (w & 3) << 6;    // 0,64,128,192
  f32x4 acc[4][4] = {};

  // Hoisted read offsets: sH swizzle low3 depends only on r16&7 (wm, mi*16
  // are multiples of 16), sB swizzle is iter-invariant.
  int aoff[4], boff[4];
#pragma unroll
  for (int mi = 0; mi < 4; ++mi) aoff[mi] = (wm + (mi << 4) + r16) << 9;
#pragma unroll
  for (int ni = 0; ni < 4; ++ni) {
    const int row = wn + (ni << 4) + r16;
    boff[ni] = (row << 5) + ((q ^ (row & 3)) << 3);
  }
  const int swzA = r16 & 7;

  int buf = 0;
  for (int iter = 0; iter < 64; ++iter) {
    if (iter < 63) stage(iter + 1, buf ^ 1);

    const int cbase = (iter & 15) << 2;          // k0>>3
    const int ch = ((cbase + q) ^ swzA) << 3;    // swizzled chunk offset (elems)
    short8 af[4], bf[4];
#pragma unroll
    for (int mi = 0; mi < 4; ++mi)
      af[mi] = *(const short8*)(sH + aoff[mi] + ch);
#pragma unroll
    for (int ni = 0; ni < 4; ++ni)
      bf[ni] = *(const short8*)(&sB[buf][0] + boff[ni]);
#pragma unroll
    for (int mi = 0; mi < 4; ++mi)
#pragma unroll
      for (int ni = 0; ni < 4; ++ni)
        acc[mi][ni] = __builtin_amdgcn_mfma_f32_16x16x32_bf16(
            af[mi], bf[ni], acc[mi][ni], 0, 0, 0);

    if ((iter & 15) == 15) {
      // End of this nt: store 128x256 sub-tile, re-zero acc.
      const int n0 = (iter >> 4) << 8;
#pragma unroll
      for (int ni = 0; ni < 4; ++ni) {
        const int col = n0 + wn + (ni << 4) + r16;
        const float bc = __bfloat162float(bias[col]);
#pragma unroll
        for (int mi = 0; mi < 4; ++mi) {
          const int rowb = m0 + wm + (mi << 4) + (q << 2);
#pragma unroll
          for (int i = 0; i < 4; ++i)
            out[(size_t)(rowb + i) * 1024 + col] = acc[mi][ni][i] + bc;
        }
      }
#pragma unroll
      for (int mi = 0; mi < 4; ++mi)
#pragma unroll
        for (int ni = 0; ni < 4; ++ni)
          acc[mi][ni] = (f32x4){0.0f, 0.0f, 0.0f, 0.0f};
    }

    __syncthreads();  // vmcnt(0)+lgkmcnt(0)+barrier: next tile ready
    buf ^= 1;
  }
}

// ---------------------------------------------------------------------------
extern "C" void kernel_launch(void* const* d_in, const int* in_sizes, int n_in,
                              void* d_out, int out_size, void* d_ws,
                              size_t ws_size, hipStream_t stream) {
  // ws layout: 0 flags (7 ints) | 256 bf16 copies (3.26MB) | 4MB Pe | 6MB Pd
  char* ws = (char*)d_ws;
  int* flags = (int*)ws;
  __hip_bfloat16* cp = (__hip_bfloat16*)(ws + 256);
  float* Pe = (float*)(ws + (4ull << 20));
  float* Pd = (float*)(ws + (6ull << 20));

  detect_kernel<<<dim3(1), dim3(512), 0, stream>>>(
      d_in[0], d_in[1], d_in[2], d_in[3], d_in[4], d_in[5], d_in[6], flags);
  convert_kernel<<<dim3((CTOT + 255) / 256), dim3(256), 0, stream>>>(
      d_in[0], d_in[1], d_in[2], d_in[3], d_in[4], d_in[5], d_in[6], flags, cp);

  const __hip_bfloat16* enc_c = cp + CU0;
  const __hip_bfloat16* dec_c = cp + CU1;
  const __hip_bfloat16* Wenc_c = cp + CU2;
  const __hip_bfloat16* benc_c = cp + CU3;
  const __hip_bfloat16* Wdec_c = cp + CU4;
  const __hip_bfloat16* Wout_c = cp + CU5;
  const __hip_bfloat16* bout_c = cp + CU6;

  proj_kernel<<<dim3(40), dim3(256), 0, stream>>>(enc_c, Wenc_c, benc_c,
                                                  dec_c, Wdec_c, Pe, Pd);
  gemm_joint<<<dim3(512), dim3(512), 0, stream>>>(
      Pe, Pd, Wout_c, bout_c, (float*)d_out);
}

// Round 3
// 402.081 us; speedup vs baseline: 1.1575x; 1.0202x over previous
//
#include <hip/hip_runtime.h>
#include <hip/hip_bf16.h>

// RNN-T joint network. B=4 T=256 U=64 D=512 J=512 V=1024.
//   Pe = enc @ W_enc^T + b_enc   (1024 x 512)  fp32 in ws
//   Pd = dec @ W_dec^T           (256  x 512)  fp32 in ws
//   out[m,:] = tanh(Pe[m>>6] + Pd[(m>>14)*64 + (m&63)]) @ W_out^T + b_out
//
// gemm_joint (round-3): BM=64 rows/block, full K=512 of H in LDS (64KB),
// sB 2x8KB double buffer -> 80KB total = 2 workgroups/CU (round-2 lesson:
// 160KB/1-WG lockstep left the CU idle at every vmcnt(0) drain; MfmaUtil 14%).
// Each block = ONE Pe row (e=blockIdx) + 64 consecutive Pd rows.
// Swizzles (rule #21, same involution both sides):
//   sH: chunk c stored/read at c ^ (row&7)                  (row stride 1KB)
//   sB: chunk c stored/read at c ^ (row&3) ^ ((row>>2)&3)   (row stride 64B;
//       round-2's ^(row&3) alone left a 4-way conflict -> 8.4M SQ_LDS_BANK_CONFLICT)

typedef __attribute__((ext_vector_type(8))) short short8;     // 8 bf16
typedef __attribute__((ext_vector_type(4))) float f32x4;

#define SZ0 524288
#define SZ1 131072
#define SZ2 262144
#define SZ3 512
#define SZ4 262144
#define SZ5 524288
#define SZ6 1024
#define CU0 0
#define CU1 524288
#define CU2 655360
#define CU3 917504
#define CU4 918016
#define CU5 1180160
#define CU6 1704448
#define CTOT 1705472

// ---------------------------------------------------------------------------
// Runtime dtype detection (unchanged).
// ---------------------------------------------------------------------------
__global__ void detect_kernel(const void* p0, const void* p1, const void* p2,
                              const void* p3, const void* p4, const void* p5,
                              const void* p6, int* flags) {
  const void* ps[7] = {p0, p1, p2, p3, p4, p5, p6};
  const int sz[7] = {SZ0, SZ1, SZ2, SZ3, SZ4, SZ5, SZ6};
  const int w = threadIdx.x >> 6;
  const int l = threadIdx.x & 63;
  if (w >= 7) return;
  const unsigned short* u = (const unsigned short*)ps[w];
  const int lim = sz[w] < 1024 ? sz[w] : 1024;
  int bad = 0;
  for (int j = l; j < lim; j += 64) {
    const unsigned e = (u[j] >> 7) & 0xFFu;
    if (e >= 0x8Eu) bad = 1;
  }
  const unsigned long long b = __ballot(bad);
  if (l == 0) flags[w] = (b != 0ULL) ? 1 : 0;
}

__global__ __launch_bounds__(256) void convert_kernel(
    const void* p0, const void* p1, const void* p2, const void* p3,
    const void* p4, const void* p5, const void* p6,
    const int* __restrict__ flags, __hip_bfloat16* __restrict__ dst) {
  const int gid = blockIdx.x * 256 + threadIdx.x;
  if (gid >= CTOT) return;
  int t, local;
  const void* p;
  if (gid < CU1)      { t = 0; local = gid - CU0; p = p0; }
  else if (gid < CU2) { t = 1; local = gid - CU1; p = p1; }
  else if (gid < CU3) { t = 2; local = gid - CU2; p = p2; }
  else if (gid < CU4) { t = 3; local = gid - CU3; p = p3; }
  else if (gid < CU5) { t = 4; local = gid - CU4; p = p4; }
  else if (gid < CU6) { t = 5; local = gid - CU5; p = p5; }
  else                { t = 6; local = gid - CU6; p = p6; }
  __hip_bfloat16 v;
  if (flags[t])
    v = __float2bfloat16(((const float*)p)[local]);
  else
    v = ((const __hip_bfloat16*)p)[local];
  dst[gid] = v;
}

// ---------------------------------------------------------------------------
// m97-structure GEMM body for the two small projections (unchanged).
// ---------------------------------------------------------------------------
__device__ __forceinline__ void gemm_bt_body(
    const __hip_bfloat16* __restrict__ A, const __hip_bfloat16* __restrict__ Bw,
    const __hip_bfloat16* __restrict__ bias, float* __restrict__ C,
    int M, int N, int K, int bid,
    __hip_bfloat16* sA, __hip_bfloat16* sB) {
  const int tid = threadIdx.x;
  const int w = tid >> 6;
  const int l = tid & 63;
  const int ntiles = N >> 7;
  const int mt = bid / ntiles;
  const int nt = bid % ntiles;
  const int m0 = mt << 7;
  const int n0 = nt << 7;
  const int wm = (w >> 1) << 6;
  const int wn = (w & 1) << 6;
  const int r16 = l & 15;
  const int q = l >> 4;

  f32x4 acc[4][4] = {};

  const int srow_in = l >> 3;
  const int scol = (l & 7) << 3;

  for (int k0 = 0; k0 < K; k0 += 64) {
#pragma unroll
    for (int i = 0; i < 4; ++i) {
      const int c = (w << 2) + i;
      const int row = (c << 3) + srow_in;
      const __hip_bfloat16* gA = A + (size_t)(m0 + row) * K + k0 + scol;
      const __hip_bfloat16* gB = Bw + (size_t)(n0 + row) * K + k0 + scol;
      __builtin_amdgcn_global_load_lds(
          (const __attribute__((address_space(1))) void*)gA,
          (__attribute__((address_space(3))) void*)(sA + (c << 9) + (l << 3)),
          16, 0, 0);
      __builtin_amdgcn_global_load_lds(
          (const __attribute__((address_space(1))) void*)gB,
          (__attribute__((address_space(3))) void*)(sB + (c << 9) + (l << 3)),
          16, 0, 0);
    }
    __syncthreads();

#pragma unroll
    for (int kk = 0; kk < 2; ++kk) {
      const int kc = (kk << 5) + (q << 3);
      short8 af[4], bf[4];
#pragma unroll
      for (int mi = 0; mi < 4; ++mi)
        af[mi] = *(const short8*)(sA + (wm + (mi << 4) + r16) * 64 + kc);
#pragma unroll
      for (int ni = 0; ni < 4; ++ni)
        bf[ni] = *(const short8*)(sB + (wn + (ni << 4) + r16) * 64 + kc);
#pragma unroll
      for (int mi = 0; mi < 4; ++mi)
#pragma unroll
        for (int ni = 0; ni < 4; ++ni)
          acc[mi][ni] = __builtin_amdgcn_mfma_f32_16x16x32_bf16(
              af[mi], bf[ni], acc[mi][ni], 0, 0, 0);
    }
    __syncthreads();
  }

#pragma unroll
  for (int ni = 0; ni < 4; ++ni) {
    const int col = n0 + wn + (ni << 4) + r16;
    const float bc = bias ? __bfloat162float(bias[col]) : 0.0f;
#pragma unroll
    for (int mi = 0; mi < 4; ++mi) {
      const int rowb = m0 + wm + (mi << 4) + (q << 2);
#pragma unroll
      for (int i = 0; i < 4; ++i)
        C[(size_t)(rowb + i) * N + col] = acc[mi][ni][i] + bc;
    }
  }
}

__global__ __launch_bounds__(256) void proj_kernel(
    const __hip_bfloat16* __restrict__ enc, const __hip_bfloat16* __restrict__ Wenc,
    const __hip_bfloat16* __restrict__ benc,
    const __hip_bfloat16* __restrict__ dec, const __hip_bfloat16* __restrict__ Wdec,
    float* __restrict__ Pe, float* __restrict__ Pd) {
  __shared__ __align__(16) __hip_bfloat16 sA[128 * 64];
  __shared__ __align__(16) __hip_bfloat16 sB[128 * 64];
  if (blockIdx.x < 32)
    gemm_bt_body(enc, Wenc, benc, Pe, 1024, 512, 512, blockIdx.x, sA, sB);
  else
    gemm_bt_body(dec, Wdec, nullptr, Pd, 256, 512, 512, blockIdx.x - 32, sA, sB);
}

// ---------------------------------------------------------------------------
// Main fused GEMM. grid = 1024 blocks (BM=64), 512 threads (8 waves),
// 2 workgroups/CU (80KB LDS). Wave tile 32x32: wm=(w>>2)*32, wn=(w&3)*32.
// 128 iters = 8 nt-chunks (BN=128) x 16 k-steps (BK=32).
// Per iter/thread: 1 global_load_lds (stage next), 4 ds_read_b128, 4 MFMA.
// ---------------------------------------------------------------------------
__global__ __launch_bounds__(512, 4) void gemm_joint(
    const float* __restrict__ Pe, const float* __restrict__ Pd,
    const __hip_bfloat16* __restrict__ Bw,
    const __hip_bfloat16* __restrict__ bias, float* __restrict__ out) {
  __shared__ __align__(16) __hip_bfloat16 sH[64 * 512];    // 64 KB
  __shared__ __align__(16) __hip_bfloat16 sB[2][128 * 32]; // 2 x 8 KB

  const int t = threadIdx.x;
  const int w = t >> 6;
  const int l = t & 63;
  const int r16 = l & 15;
  const int q = l >> 4;
  const int m0 = blockIdx.x << 6;

  // STAGE: sB[buf] <- W_out tile (nt = iter>>4, k0 = (iter&15)*32).
  // Linear LDS dest (gload_lds), source chunk pre-swizzled by the involution.
  auto stage = [&](int iter, int buf) {
    const int n0 = (iter >> 4) << 7;
    const int k0 = (iter & 15) << 5;
    const int row = t >> 2;           // 0..127
    const int cc = t & 3;             // 16B chunk within row
    const int s = (row & 3) ^ ((row >> 2) & 3);
    const __hip_bfloat16* src =
        Bw + (size_t)(n0 + row) * 512 + k0 + ((cc ^ s) << 3);
    __builtin_amdgcn_global_load_lds(
        (const __attribute__((address_space(1))) void*)src,
        (__attribute__((address_space(3))) void*)(&sB[buf][0] + (t << 3)),
        16, 0, 0);
  };

  // Prologue: issue first B-tile; tanh phase hides its L2 latency.
  stage(0, 0);

  // Phase 1: sH = tanh(Pe[e] + Pd[d]).  This block: e = blockIdx (one Pe
  // row broadcast to all 64 H rows), d = (blockIdx>>8)*64 + r.
  {
    const int r = t & 63;           // H row
    const int seg = t >> 6;         // 0..7, 64-col segment
    const int e = blockIdx.x;
    const int d = ((blockIdx.x >> 8) << 6) | r;
    const float* pe = Pe + (size_t)e * 512 + (seg << 6);
    const float* pd = Pd + (size_t)d * 512 + (seg << 6);
#pragma unroll
    for (int i = 0; i < 8; ++i) {
      const int cc = (seg << 3) + i;            // chunk index 0..63
      const f32x4 a0 = *(const f32x4*)(pe + (i << 3));
      const f32x4 a1 = *(const f32x4*)(pe + (i << 3) + 4);
      const f32x4 b0 = *(const f32x4*)(pd + (i << 3));
      const f32x4 b1 = *(const f32x4*)(pd + (i << 3) + 4);
      short8 hv;
#pragma unroll
      for (int jj = 0; jj < 4; ++jj) {
        float s = a0[jj] + b0[jj];
        float tv = 1.0f - 2.0f / (__expf(2.0f * s) + 1.0f);
        __hip_bfloat16 hb = __float2bfloat16(tv);
        hv[jj] = *(const short*)&hb;
        s = a1[jj] + b1[jj];
        tv = 1.0f - 2.0f / (__expf(2.0f * s) + 1.0f);
        hb = __float2bfloat16(tv);
        hv[4 + jj] = *(const short*)&hb;
      }
      *(short8*)(sH + (r << 9) + ((cc ^ (r & 7)) << 3)) = hv;
    }
  }
  __syncthreads();  // drains vmcnt (stage 0) + lgkmcnt (sH writes)

  const int wm = (w >> 2) << 5;   // 0 or 32
  const int wn = (w & 3) << 5;    // 0,32,64,96
  f32x4 acc[2][2] = {};

  // Hoisted LDS read offsets (elements).
  int aoff[2], boff[2];
#pragma unroll
  for (int mi = 0; mi < 2; ++mi) aoff[mi] = (wm + (mi << 4) + r16) << 9;
#pragma unroll
  for (int ni = 0; ni < 2; ++ni) {
    const int row = wn + (ni << 4) + r16;
    const int s = (row & 3) ^ ((row >> 2) & 3);
    boff[ni] = (row << 5) + ((q ^ s) << 3);
  }
  const int swzA = r16 & 7;

  int buf = 0;
  for (int iter = 0; iter < 128; ++iter) {
    if (iter < 127) stage(iter + 1, buf ^ 1);

    const int cbase = (iter & 15) << 2;          // k chunk base
    const int ch = ((cbase + q) ^ swzA) << 3;    // swizzled sH offset (elems)
    short8 af[2], bf[2];
#pragma unroll
    for (int mi = 0; mi < 2; ++mi)
      af[mi] = *(const short8*)(sH + aoff[mi] + ch);
#pragma unroll
    for (int ni = 0; ni < 2; ++ni)
      bf[ni] = *(const short8*)(&sB[buf][0] + boff[ni]);
#pragma unroll
    for (int mi = 0; mi < 2; ++mi)
#pragma unroll
      for (int ni = 0; ni < 2; ++ni)
        acc[mi][ni] = __builtin_amdgcn_mfma_f32_16x16x32_bf16(
            af[mi], bf[ni], acc[mi][ni], 0, 0, 0);

    if ((iter & 15) == 15) {
      // End of this nt-chunk: store 64x128 sub-tile, re-zero acc.
      const int n0 = (iter >> 4) << 7;
#pragma unroll
      for (int ni = 0; ni < 2; ++ni) {
        const int col = n0 + wn + (ni << 4) + r16;
        const float bc = __bfloat162float(bias[col]);
#pragma unroll
        for (int mi = 0; mi < 2; ++mi) {
          const int rowb = m0 + wm + (mi << 4) + (q << 2);
#pragma unroll
          for (int i = 0; i < 4; ++i)
            out[(size_t)(rowb + i) * 1024 + col] = acc[mi][ni][i] + bc;
        }
      }
#pragma unroll
      for (int mi = 0; mi < 2; ++mi)
#pragma unroll
        for (int ni = 0; ni < 2; ++ni)
          acc[mi][ni] = (f32x4){0.0f, 0.0f, 0.0f, 0.0f};
    }

    __syncthreads();  // next tile ready; sibling WG on the CU covers the drain
    buf ^= 1;
  }
}

// ---------------------------------------------------------------------------
extern "C" void kernel_launch(void* const* d_in, const int* in_sizes, int n_in,
                              void* d_out, int out_size, void* d_ws,
                              size_t ws_size, hipStream_t stream) {
  // ws layout: 0 flags (7 ints) | 256 bf16 copies (3.26MB) | 4MB Pe | 6MB Pd
  char* ws = (char*)d_ws;
  int* flags = (int*)ws;
  __hip_bfloat16* cp = (__hip_bfloat16*)(ws + 256);
  float* Pe = (float*)(ws + (4ull << 20));
  float* Pd = (float*)(ws + (6ull << 20));

  detect_kernel<<<dim3(1), dim3(512), 0, stream>>>(
      d_in[0], d_in[1], d_in[2], d_in[3], d_in[4], d_in[5], d_in[6], flags);
  convert_kernel<<<dim3((CTOT + 255) / 256), dim3(256), 0, stream>>>(
      d_in[0], d_in[1], d_in[2], d_in[3], d_in[4], d_in[5], d_in[6], flags, cp);

  const __hip_bfloat16* enc_c = cp + CU0;
  const __hip_bfloat16* dec_c = cp + CU1;
  const __hip_bfloat16* Wenc_c = cp + CU2;
  const __hip_bfloat16* benc_c = cp + CU3;
  const __hip_bfloat16* Wdec_c = cp + CU4;
  const __hip_bfloat16* Wout_c = cp + CU5;
  const __hip_bfloat16* bout_c = cp + CU6;

  proj_kernel<<<dim3(40), dim3(256), 0, stream>>>(enc_c, Wenc_c, benc_c,
                                                  dec_c, Wdec_c, Pe, Pd);
  gemm_joint<<<dim3(1024), dim3(512), 0, stream>>>(
      Pe, Pd, Wout_c, bout_c, (float*)d_out);
}